// Round 3
// baseline (698.917 us; speedup 1.0000x reference)
//
#include <hip/hip_runtime.h>
#include <hip/hip_bf16.h>
#include <stdint.h>

// Problem constants (reference: B=128, No=128, Nr=512, D=512)
#define C_B   128
#define C_NO  128
#define C_NR  512
#define C_D   512

typedef __attribute__((ext_vector_type(8))) short  short8;   // 8 bf16 = 4 VGPRs (MFMA A/B frag)
typedef __attribute__((ext_vector_type(4))) float  floatx4;  // MFMA C/D frag

__device__ __forceinline__ void load_lds16(const void* g, void* lds) {
  // 16B/lane global->LDS DMA; LDS dest = wave-uniform base + lane*16 [m97/m104]
  __builtin_amdgcn_global_load_lds(
      (const __attribute__((address_space(1))) void*)g,
      (__attribute__((address_space(3))) void*)lds, 16, 0, 0);
}

__device__ __forceinline__ short bfs(float x) {
  __hip_bfloat16 h = __float2bfloat16(x);
  return *reinterpret_cast<short*>(&h);
}

// ---------------------------------------------------------------------------
// Weight transpose+convert: W fp32 (K x N) row-major -> WT bf16 (N x K).
// Input values are on the bf16 grid, so the conversion is exact.
// ---------------------------------------------------------------------------
__global__ void transpose_cvt_k(const float* __restrict__ W,
                                __hip_bfloat16* __restrict__ WT, int K, int N) {
  __shared__ float tile[32][33];
  const int k0 = blockIdx.x * 32;
  const int n0 = blockIdx.y * 32;
  const int tx = threadIdx.x & 31;
  const int ty = threadIdx.x >> 5;  // 0..7
#pragma unroll
  for (int i = ty; i < 32; i += 8)
    tile[i][tx] = W[(size_t)(k0 + i) * N + n0 + tx];
  __syncthreads();
#pragma unroll
  for (int i = ty; i < 32; i += 8)
    WT[(size_t)(n0 + i) * K + k0 + tx] = __float2bfloat16(tile[tx][i]);
}

// new_obj = obj passthrough, fp32 bit-copy (runs LAST: overwrites WT_rela scratch)
__global__ void copy16_k(const uint4* __restrict__ src, uint4* __restrict__ dst) {
  const size_t i = (size_t)blockIdx.x * blockDim.x + threadIdx.x;
  dst[i] = src[i];
}

// ---------------------------------------------------------------------------
// Fused GEMM: 128x128 tile, BK=32, 256 threads (4 waves, 2x2), each wave 4x4
// tiles of mfma_f32_16x16x32_bf16. A: fp32 global -> cvt -> ds_write_b128.
// B: bf16 WT via global_load_lds width-16.
//
// MODE 0: C = A0 @ WT^T + bias                          (attr projection, fp32 out)
// MODE 1: C = relu([obj|attrS] @ WT^T + bias) + attrS   (new_attr)
// MODE 2: C = (relu([obj[s]|rela|obj[o]] @ WT^T + bias) + rela) * mask
// Each BK=32 slab lies inside one 512-wide concat region -> wave-uniform branch.
// ---------------------------------------------------------------------------
template <int MODE, int K>
__global__ __launch_bounds__(256) void gemm_k(
    const float* __restrict__ A0,            // mode0: attr_vecs; mode1/2: obj2
    const float* __restrict__ A1,            // mode1: attrS; mode2: rela2
    const int* __restrict__ edges,           // mode2 only
    const __hip_bfloat16* __restrict__ WT,   // (N x K) bf16 transposed weights
    const float* __restrict__ bias,          // (512) fp32
    const float* __restrict__ resid,         // mode1: attrS; mode2: rela2 (fp32)
    const float* __restrict__ mask,          // mode2: rela_masks per-row (fp32)
    float* __restrict__ Cout) {
  constexpr int BK = 32;
  __shared__ __align__(16) __hip_bfloat16 As[128 * BK];  // [m][k] bf16
  __shared__ __align__(16) __hip_bfloat16 Bs[128 * BK];  // [n][k] bf16 (DMA layout)
  __shared__ int sRow[128];
  __shared__ int oRow[128];

  const int t = threadIdx.x;
  const int lane = t & 63;
  const int w = t >> 6;
  const int m0 = blockIdx.y * 128;
  const int n0 = blockIdx.x * 128;

  if constexpr (MODE == 2) {
    if (t < 128) {
      const int r = m0 + t;
      const int b = r >> 9;  // r / Nr, Nr=512
      sRow[t] = b * C_NO + edges[2 * r];
      oRow[t] = b * C_NO + edges[2 * r + 1];
    }
    __syncthreads();
  }

  // staging geometry: thread t (+ half j) covers row j*64 + t/4, cols (t%4)*8..+8
  const int aRow = t >> 2;
  const int aCol = (t & 3) * 8;

  floatx4 acc[4][4];
#pragma unroll
  for (int i = 0; i < 4; ++i)
#pragma unroll
    for (int j = 0; j < 4; ++j) acc[i][j] = (floatx4)0.0f;

  const int wm = (w >> 1) * 64;  // wave m-offset in tile
  const int wn = (w & 1) * 64;   // wave n-offset
  const int fm = lane & 15;
  const int kq = (lane >> 4) * 8;

  for (int kt = 0; kt < K; kt += BK) {
    // B: bf16 weights, direct-to-LDS DMA (dest = wave-uniform base + lane*16)
#pragma unroll
    for (int j = 0; j < 2; ++j)
      load_lds16(WT + (size_t)(n0 + j * 64 + aRow) * K + kt + aCol,
                 &Bs[j * 2048 + w * 512]);
    // A: fp32 global -> registers -> cvt -> bf16 LDS (ds_write_b128)
#pragma unroll
    for (int j = 0; j < 2; ++j) {
      const int m = j * 64 + aRow;
      const int kg = kt + aCol;
      const float* srcA;
      if constexpr (MODE == 0) {
        srcA = A0 + (size_t)(m0 + m) * K + kg;
      } else if constexpr (MODE == 1) {
        srcA = (kg < C_D) ? A0 + (size_t)(m0 + m) * C_D + kg
                          : A1 + (size_t)(m0 + m) * C_D + (kg - C_D);
      } else {
        const int region = kg >> 9;  // wave-uniform (kt mult of 32, aCol<32)
        if (region == 0)
          srcA = A0 + (size_t)sRow[m] * C_D + kg;
        else if (region == 1)
          srcA = A1 + (size_t)(m0 + m) * C_D + (kg - C_D);
        else
          srcA = A0 + (size_t)oRow[m] * C_D + (kg - 2 * C_D);
      }
      const float4 f0 = *reinterpret_cast<const float4*>(srcA);
      const float4 f1 = *reinterpret_cast<const float4*>(srcA + 4);
      short8 v;
      v[0] = bfs(f0.x); v[1] = bfs(f0.y); v[2] = bfs(f0.z); v[3] = bfs(f0.w);
      v[4] = bfs(f1.x); v[5] = bfs(f1.y); v[6] = bfs(f1.z); v[7] = bfs(f1.w);
      *reinterpret_cast<short8*>(&As[j * 2048 + t * 8]) = v;  // == [m][kg&31]
    }
    __syncthreads();

    short8 af[4], bf[4];
#pragma unroll
    for (int mi = 0; mi < 4; ++mi)
      af[mi] = *reinterpret_cast<const short8*>(&As[(wm + mi * 16 + fm) * BK + kq]);
#pragma unroll
    for (int ni = 0; ni < 4; ++ni)
      bf[ni] = *reinterpret_cast<const short8*>(&Bs[(wn + ni * 16 + fm) * BK + kq]);
#pragma unroll
    for (int mi = 0; mi < 4; ++mi)
#pragma unroll
      for (int ni = 0; ni < 4; ++ni)
        acc[mi][ni] =
            __builtin_amdgcn_mfma_f32_16x16x32_bf16(af[mi], bf[ni], acc[mi][ni], 0, 0, 0);
    __syncthreads();
  }

  // Epilogue. C/D mapping: col = lane&15, row = (lane>>4)*4 + reg  [m89-verified]
  float bv[4];
#pragma unroll
  for (int ni = 0; ni < 4; ++ni)
    bv[ni] = bias[n0 + wn + ni * 16 + fm];

#pragma unroll
  for (int mi = 0; mi < 4; ++mi) {
    const int rb = m0 + wm + mi * 16 + (lane >> 4) * 4;
#pragma unroll
    for (int i = 0; i < 4; ++i) {
      const int cm = rb + i;
      float mv = 1.0f;
      if constexpr (MODE == 2) mv = mask[cm];
#pragma unroll
      for (int ni = 0; ni < 4; ++ni) {
        const int cn = n0 + wn + ni * 16 + fm;
        float v = acc[mi][ni][i] + bv[ni];
        if constexpr (MODE == 0) {
          Cout[(size_t)cm * C_D + cn] = v;
        } else {
          v = fmaxf(v, 0.0f) + resid[(size_t)cm * C_D + cn];
          if constexpr (MODE == 2) v *= mv;
          Cout[(size_t)cm * C_D + cn] = v;
        }
      }
    }
  }
}

extern "C" void kernel_launch(void* const* d_in, const int* in_sizes, int n_in,
                              void* d_out, int out_size, void* d_ws, size_t ws_size,
                              hipStream_t stream) {
  // Reference dtypes: all float tensors fp32 (values bf16-grid-quantized),
  // edges int32, outputs fp32.
  const float* obj       = (const float*)d_in[0];   // (128,128,512)
  const float* attr_vecs = (const float*)d_in[1];   // (128,128,1024)
  const float* rela      = (const float*)d_in[2];   // (128,512,512)
  const int*   edges     = (const int*)d_in[3];     // (128,512,2)
  const float* masks     = (const float*)d_in[4];   // (128,512,1)
  const float* W_att     = (const float*)d_in[5];   // (1024,512)
  const float* b_att     = (const float*)d_in[6];
  const float* W_attr    = (const float*)d_in[7];   // (1024,512)
  const float* b_attr    = (const float*)d_in[8];
  const float* W_rela    = (const float*)d_in[9];   // (1536,512)
  const float* b_rela    = (const float*)d_in[10];

  float* out      = (float*)d_out;
  float* out_obj  = out;                 //  8,388,608 fp32
  float* out_attr = out + 8388608;       //  8,388,608 fp32
  float* out_rela = out + 16777216;      // 33,554,432 fp32

  // ZERO-workspace plan (d_ws untouched): scratch in d_out regions written
  // after the scratch is dead.
  //   out_rela[0        .. 8388608)  fp32 : attrS (attr intermediate)
  //   out_rela[8388608  .. 8650752)  as bf16: WT_att  (512x1024)
  //   out_rela[8650752  .. 8912896)  as bf16: WT_attr (512x1024)
  //   out_obj [0        .. 393216)   as bf16: WT_rela (512x1536)
  float*          attrS   = out_rela;
  __hip_bfloat16* WT_att  = (__hip_bfloat16*)(out_rela + 8388608);
  __hip_bfloat16* WT_attr = (__hip_bfloat16*)(out_rela + 8650752);
  __hip_bfloat16* WT_rela = (__hip_bfloat16*)out_obj;

  // 1) Weight transposes + fp32->bf16 (exact: grid values)
  transpose_cvt_k<<<dim3(32, 16), 256, 0, stream>>>(W_att, WT_att, 1024, 512);
  transpose_cvt_k<<<dim3(32, 16), 256, 0, stream>>>(W_attr, WT_attr, 1024, 512);
  transpose_cvt_k<<<dim3(48, 16), 256, 0, stream>>>(W_rela, WT_rela, 1536, 512);

  // 2) attr = attr_vecs @ W_att + b_att -> attrS (fp32 scratch in out_rela)
  gemm_k<0, 1024><<<dim3(4, 128), 256, 0, stream>>>(
      attr_vecs, nullptr, nullptr, WT_att, b_att, nullptr, nullptr, attrS);

  // 3) new_attr = relu([obj|attrS] @ W_attr + b_attr) + attrS -> out_attr
  gemm_k<1, 1024><<<dim3(4, 128), 256, 0, stream>>>(
      obj, attrS, nullptr, WT_attr, b_attr, attrS, nullptr, out_attr);

  // 4) new_rela = (relu([obj[s]|rela|obj[o]] @ W_rela + b_rela) + rela) * mask
  //    Reads only inputs + WT_rela (in out_obj); overwrites all out_rela scratch.
  gemm_k<2, 1536><<<dim3(4, 512), 256, 0, stream>>>(
      obj, rela, edges, WT_rela, b_rela, rela, masks, out_rela);

  // 5) new_obj = obj (exact fp32 copy; overwrites WT_rela scratch). 33.5 MB.
  copy16_k<<<8192, 256, 0, stream>>>((const uint4*)obj, (uint4*)out_obj);
}